// Round 1
// baseline (1082.939 us; speedup 1.0000x reference)
//
#include <hip/hip_runtime.h>

// NerfModel: voxel-grid gather + SH-deg2 eval.
//   inputs : x (M,3) f32, d (M,3) f32, voxel_grid (200,200,200,28) f32
//   outputs: color (M,3) f32 then sigma (M,) f32, concatenated in d_out.
// Memory-bound; the masked random 112 B gather from the 896 MB grid dominates.

constexpr float kScale = 1.5f;
constexpr int   kN     = 200;

__global__ __launch_bounds__(256) void nerf_fwd(
    const float* __restrict__ x,
    const float* __restrict__ dir,
    const float* __restrict__ grid,
    float* __restrict__ out,      // [3M color][M sigma]
    int M)
{
    int i = blockIdx.x * blockDim.x + threadIdx.x;
    if (i >= M) return;

    const float x0 = x[3 * i + 0];
    const float x1 = x[3 * i + 1];
    const float x2 = x[3 * i + 2];

    const bool mask = (fabsf(x0) < kScale) && (fabsf(x1) < kScale) && (fabsf(x2) < kScale);

    float c0 = 0.0f, c1 = 0.0f, c2 = 0.0f, sg = 0.0f;

    if (mask) {
        // idx = clip((int)(x / (2*SCALE/N) + N/2), 0, N-1); (int) truncates toward 0, same as astype(int32)
        const float h = 2.0f * kScale / (float)kN;   // 0.015f
        int i0 = (int)(x0 / h + 0.5f * (float)kN);
        int i1 = (int)(x1 / h + 0.5f * (float)kN);
        int i2 = (int)(x2 / h + 0.5f * (float)kN);
        i0 = min(max(i0, 0), kN - 1);
        i1 = min(max(i1, 0), kN - 1);
        i2 = min(max(i2, 0), kN - 1);

        const size_t voff = (size_t)((i0 * kN + i1) * kN + i2) * 28u;
        const float4* __restrict__ g4 = reinterpret_cast<const float4*>(grid + voff);
        // 28 floats = 7 aligned float4 loads (record stride 112 B = 7*16 B)
        const float4 t0 = g4[0];
        const float4 t1 = g4[1];
        const float4 t2 = g4[2];
        const float4 t3 = g4[3];
        const float4 t4 = g4[4];
        const float4 t5 = g4[5];
        const float4 t6 = g4[6];
        const float t[28] = {
            t0.x, t0.y, t0.z, t0.w,
            t1.x, t1.y, t1.z, t1.w,
            t2.x, t2.y, t2.z, t2.w,
            t3.x, t3.y, t3.z, t3.w,
            t4.x, t4.y, t4.z, t4.w,
            t5.x, t5.y, t5.z, t5.w,
            t6.x, t6.y, t6.z, t6.w
        };

        sg = fmaxf(t[0], 0.0f);

        const float dx = dir[3 * i + 0];
        const float dy = dir[3 * i + 1];
        const float dz = dir[3 * i + 2];

        // SH basis (shared across the 3 color channels)
        const float b0 = 0.282095f;
        const float b1 = -0.488603f * dy;
        const float b2 =  0.488603f * dz;
        const float b3 = -0.488603f * dx;
        const float b4 =  1.092548f * dx * dy;
        const float b5 = -1.092548f * dy * dz;
        const float b6 =  0.315392f * (2.0f * dz * dz - dx * dx - dy * dy);
        const float b7 = -1.092548f * dx * dz;
        const float b8 =  0.546274f * (dx * dx - dy * dy);

        c0 = b0 * t[1]  + b1 * t[2]  + b2 * t[3]  + b3 * t[4]  + b4 * t[5]
           + b5 * t[6]  + b6 * t[7]  + b7 * t[8]  + b8 * t[9];
        c1 = b0 * t[10] + b1 * t[11] + b2 * t[12] + b3 * t[13] + b4 * t[14]
           + b5 * t[15] + b6 * t[16] + b7 * t[17] + b8 * t[18];
        c2 = b0 * t[19] + b1 * t[20] + b2 * t[21] + b3 * t[22] + b4 * t[23]
           + b5 * t[24] + b6 * t[25] + b7 * t[26] + b8 * t[27];
    }

    out[3 * i + 0] = c0;
    out[3 * i + 1] = c1;
    out[3 * i + 2] = c2;
    out[(size_t)3 * M + i] = sg;
}

extern "C" void kernel_launch(void* const* d_in, const int* in_sizes, int n_in,
                              void* d_out, int out_size, void* d_ws, size_t ws_size,
                              hipStream_t stream) {
    const float* x    = (const float*)d_in[0];
    const float* dir  = (const float*)d_in[1];
    const float* grid = (const float*)d_in[2];
    float* out = (float*)d_out;

    const int M = in_sizes[0] / 3;   // 4194304
    const int block = 256;
    const int grid_dim = (M + block - 1) / block;
    nerf_fwd<<<grid_dim, block, 0, stream>>>(x, dir, grid, out, M);
}